// Round 5
// baseline (74786.829 us; speedup 1.0000x reference)
//
#include <hip/hip_runtime.h>
#include <hip/hip_cooperative_groups.h>
#include <hip/hip_bf16.h>
#include <math.h>

namespace cg = cooperative_groups;

#define B 64
#define T 128
#define S 128
#define E 512
#define H 1024
#define D 1024
#define KDIM 1024
#define G3 3072

__device__ __forceinline__ float sigmoidf_(float x) { return 1.f / (1.f + expf(-x)); }

// ---------------------------------------------------------------------------
// dotN: per-lane dot products of A-row chunk vs NR weight rows.
// arow: this lane's A pointer at its wave's K-window. nsc: #32-float subchunks
// (K coverage per wave = nsc*32 floats; wave window stride is set by caller).
// ---------------------------------------------------------------------------
template<int NR>
__device__ __forceinline__ void dotN(const float* __restrict__ arow,
                                     const float* const* __restrict__ ws,
                                     int nsc, float* __restrict__ acc) {
  for (int sc = 0; sc < nsc; ++sc) {
    float av[32];
    const float4* ap = (const float4*)(arow + sc * 32);
#pragma unroll
    for (int q = 0; q < 8; ++q) {
      float4 v = ap[q];
      av[4*q] = v.x; av[4*q+1] = v.y; av[4*q+2] = v.z; av[4*q+3] = v.w;
    }
#pragma unroll
    for (int rr = 0; rr < NR; ++rr) {
      const float4* wp = (const float4*)(ws[rr] + sc * 32);
      float s = acc[rr];
#pragma unroll
      for (int q = 0; q < 8; ++q) {
        float4 w = wp[q];
        s = fmaf(av[4*q],   w.x, s);
        s = fmaf(av[4*q+1], w.y, s);
        s = fmaf(av[4*q+2], w.z, s);
        s = fmaf(av[4*q+3], w.w, s);
      }
      acc[rr] = s;
    }
  }
}

// ---------------------------------------------------------------------------
// 128x128-tile f32 GEMM: C[M,N] = A @ W^T (+bias). 8x8 per thread, K-tile 16.
// SRC 0: plain A (lda). SRC 1: gi1 rows (b,tl) -> reversed_input. SRC 2: gi2
// rows (b,tl) -> [y_states | rnn_flip] k-split at 1024.
// ---------------------------------------------------------------------------
template<int SRC>
__global__ __launch_bounds__(256) void gemm128(
    const float* __restrict__ A1, const float* __restrict__ A2, int lda,
    const float* __restrict__ W, int ldw, const float* __restrict__ bias,
    float* __restrict__ C, int ldc, int Kd, int c0, int chLog) {
  __shared__ __align__(16) float As[16][132];
  __shared__ __align__(16) float Ws[16][132];
  const int bm = blockIdx.y * 128;
  const int bn = blockIdx.x * 128;
  const int tid = threadIdx.x;
  const int tr = tid >> 4, tc = tid & 15;
  float acc[8][8];
#pragma unroll
  for (int i = 0; i < 8; ++i)
#pragma unroll
    for (int j = 0; j < 8; ++j) acc[i][j] = 0.f;

  for (int k0 = 0; k0 < Kd; k0 += 16) {
#pragma unroll
    for (int l = 0; l < 8; ++l) {
      int i = tid + l * 256;
      int r = i >> 4, kk = i & 15;
      int rg = bm + r;
      int k = k0 + kk;
      float v;
      if (SRC == 0) {
        v = A1[(size_t)rg * lda + k];
      } else {
        int b = rg >> chLog, tl = rg & ((1 << chLog) - 1);
        int trow = b * T + c0 + tl;
        if (SRC == 1) v = A1[(size_t)trow * E + k];
        else v = (k < 1024) ? A1[(size_t)trow * 1024 + k]
                            : A2[(size_t)trow * 1024 + (k - 1024)];
      }
      As[kk][r] = v;
    }
#pragma unroll
    for (int l = 0; l < 8; ++l) {
      int i = tid + l * 256;
      int c = i >> 4, kk = i & 15;
      Ws[kk][c] = W[(size_t)(bn + c) * ldw + k0 + kk];
    }
    __syncthreads();
#pragma unroll
    for (int kk = 0; kk < 16; ++kk) {
      float a[8], w[8];
      *(float4*)&a[0] = *(const float4*)&As[kk][tr * 8];
      *(float4*)&a[4] = *(const float4*)&As[kk][tr * 8 + 4];
      *(float4*)&w[0] = *(const float4*)&Ws[kk][tc * 8];
      *(float4*)&w[4] = *(const float4*)&Ws[kk][tc * 8 + 4];
#pragma unroll
      for (int i = 0; i < 8; ++i)
#pragma unroll
        for (int j = 0; j < 8; ++j)
          acc[i][j] = fmaf(a[i], w[j], acc[i][j]);
    }
    __syncthreads();
  }
#pragma unroll
  for (int i = 0; i < 8; ++i) {
    int rg = bm + tr * 8 + i;
#pragma unroll
    for (int j = 0; j < 8; ++j) {
      int cc = bn + tc * 8 + j;
      float bv = bias ? bias[cc] : 0.f;
      C[(size_t)rg * ldc + cc] = acc[i][j] + bv;
    }
  }
}

// ---------------------------------------------------------------------------
// Scan 1 megakernel: per step one fused (gh GEMM + GRU) phase, 1 grid sync.
// ---------------------------------------------------------------------------
struct S1Args {
  const float* gi; const float* Whh; const float* bhh;
  float* hA; float* hB; float* flip; int c0; int CH;
};

__global__ __launch_bounds__(256, 2) void scan1_mega(S1Args a) {
  cg::grid_group grid = cg::this_grid();
  const int bid = blockIdx.x, NB = gridDim.x, tid = threadIdx.x;
  const int wv = tid >> 6, lane = tid & 63;
  __shared__ float red[4][6][64];
  for (int tl = 0; tl < a.CH; ++tl) {
    const int t = a.c0 + tl;
    const float* hprev = (t & 1) ? a.hB : a.hA;
    float* hcur = (t & 1) ? a.hA : a.hB;
    for (int task = bid; task < 512; task += NB) {
      const int j0 = task * 2;
      float acc[6] = {0.f, 0.f, 0.f, 0.f, 0.f, 0.f};
      const float* arow = hprev + (size_t)lane * H + wv * 256;
      const float* ws[6];
#pragma unroll
      for (int jj = 0; jj < 2; ++jj)
#pragma unroll
        for (int g = 0; g < 3; ++g)
          ws[jj * 3 + g] = a.Whh + (size_t)(g * H + j0 + jj) * H + wv * 256;
      dotN<6>(arow, ws, 8, acc);
#pragma unroll
      for (int rr = 0; rr < 6; ++rr) red[wv][rr][lane] = acc[rr];
      __syncthreads();
      if (tid < 128) {
        int jj = tid >> 6, b = tid & 63, j = j0 + jj;
        float ghr = red[0][jj*3+0][b] + red[1][jj*3+0][b] + red[2][jj*3+0][b] + red[3][jj*3+0][b] + a.bhh[j];
        float ghz = red[0][jj*3+1][b] + red[1][jj*3+1][b] + red[2][jj*3+1][b] + red[3][jj*3+1][b] + a.bhh[H + j];
        float ghn = red[0][jj*3+2][b] + red[1][jj*3+2][b] + red[2][jj*3+2][b] + red[3][jj*3+2][b] + a.bhh[2*H + j];
        const float* prow = a.gi + (size_t)(b * a.CH + tl) * G3;
        float r = sigmoidf_(prow[j] + ghr);
        float z = sigmoidf_(prow[H + j] + ghz);
        float n = tanhf(prow[2*H + j] + r * ghn);
        float hnew = (1.f - z) * n + z * hprev[(size_t)b * H + j];
        hcur[(size_t)b * H + j] = hnew;
        a.flip[((size_t)b * T + (T - 1 - t)) * H + j] = hnew;
      }
      __syncthreads();
    }
    grid.sync();
  }
}

// ---------------------------------------------------------------------------
// Scan 2 megakernel: 5 grid syncs per step.
// ---------------------------------------------------------------------------
struct S2Args {
  const float* gi; const float* Wih; const float* Whh; const float* bhh;
  const float* corrW; const float* corrB; const float* rewW; const float* rewB;
  const float* qW; const float* avW; const float* avB; const float* eW;
  const float* pk; const float* enc;
  float* uv; float* hA; float* hB; float* ctx; float* pq;
  float* corrT; float* attH; float* rew; float* energ;
  float* oC; float* oR; float* oA;
  int c0; int CH;
};

__global__ __launch_bounds__(256, 2) void scan2_mega(S2Args a) {
  cg::grid_group grid = cg::this_grid();
  const int bid = blockIdx.x, NB = gridDim.x, tid = threadIdx.x;
  const int wv = tid >> 6, lane = tid & 63;
  __shared__ float red[4][8][64];
  for (int tl = 0; tl < a.CH; ++tl) {
    const int t = a.c0 + tl;
    const float* hprev = (t & 1) ? a.hB : a.hA;
    float* hcur = (t & 1) ? a.hA : a.hB;

    // ---- Phase AB: GRU gates GEMM (uv K=2048 + h K=1024) + GRU cell ----
    for (int task = bid; task < 512; task += NB) {
      const int j0 = task * 2;
      float aU[6] = {0.f, 0.f, 0.f, 0.f, 0.f, 0.f};
      float aH[6] = {0.f, 0.f, 0.f, 0.f, 0.f, 0.f};
      {
        const float* arow = a.uv + (size_t)lane * 2048 + wv * 512;
        const float* ws[6];
#pragma unroll
        for (int jj = 0; jj < 2; ++jj)
#pragma unroll
          for (int g = 0; g < 3; ++g)
            ws[jj * 3 + g] = a.Wih + (size_t)(g * H + j0 + jj) * 4096 + 2048 + wv * 512;
        dotN<6>(arow, ws, 16, aU);
      }
      {
        const float* arow = hprev + (size_t)lane * H + wv * 256;
        const float* ws[6];
#pragma unroll
        for (int jj = 0; jj < 2; ++jj)
#pragma unroll
          for (int g = 0; g < 3; ++g)
            ws[jj * 3 + g] = a.Whh + (size_t)(g * H + j0 + jj) * H + wv * 256;
        dotN<6>(arow, ws, 8, aH);
      }
#pragma unroll
      for (int jj = 0; jj < 2; ++jj) {
        red[wv][jj*4+0][lane] = aU[jj*3+0] + aH[jj*3+0];
        red[wv][jj*4+1][lane] = aU[jj*3+1] + aH[jj*3+1];
        red[wv][jj*4+2][lane] = aU[jj*3+2];
        red[wv][jj*4+3][lane] = aH[jj*3+2];
      }
      __syncthreads();
      if (tid < 128) {
        int jj = tid >> 6, b = tid & 63, j = j0 + jj;
        float ar  = red[0][jj*4+0][b] + red[1][jj*4+0][b] + red[2][jj*4+0][b] + red[3][jj*4+0][b];
        float az  = red[0][jj*4+1][b] + red[1][jj*4+1][b] + red[2][jj*4+1][b] + red[3][jj*4+1][b];
        float anu = red[0][jj*4+2][b] + red[1][jj*4+2][b] + red[2][jj*4+2][b] + red[3][jj*4+2][b];
        float anh = red[0][jj*4+3][b] + red[1][jj*4+3][b] + red[2][jj*4+3][b] + red[3][jj*4+3][b];
        const float* prow = a.gi + (size_t)(b * a.CH + tl) * G3;
        float r = sigmoidf_(prow[j] + ar + a.bhh[j]);
        float z = sigmoidf_(prow[H + j] + az + a.bhh[H + j]);
        float gin = prow[2*H + j] + anu;
        float ghn = anh + a.bhh[2*H + j];
        float n = tanhf(gin + r * ghn);
        float hnew = (1.f - z) * n + z * hprev[(size_t)b * H + j];
        hcur[(size_t)b * H + j] = hnew;
      }
      __syncthreads();
    }
    grid.sync();

    // ---- Phase C: h-projections (corr | query | attv_h | reward) ----
    for (int task = bid; task < 385; task += NB) {
      const float* Wb; int ldw, n0, nrows;
      if (task < 128)      { Wb = a.corrW; ldw = H;    n0 = task * 8;         nrows = 8; }
      else if (task < 256) { Wb = a.qW;    ldw = H;    n0 = (task - 128) * 8; nrows = 8; }
      else if (task < 384) { Wb = a.avW;   ldw = 2048; n0 = (task - 256) * 8; nrows = 8; }
      else                 { Wb = a.rewW;  ldw = H;    n0 = 0;                nrows = 2; }
      float acc[8] = {0.f,0.f,0.f,0.f,0.f,0.f,0.f,0.f};
      const float* arow = hcur + (size_t)lane * H + wv * 256;
      const float* ws[8];
#pragma unroll
      for (int jj = 0; jj < 8; ++jj) {
        int rr = (jj < nrows) ? (n0 + jj) : n0;
        ws[jj] = Wb + (size_t)rr * ldw + wv * 256;
      }
      dotN<8>(arow, ws, 8, acc);   // nsc=8: full 256-float window per wave (BUGFIX)
#pragma unroll
      for (int jj = 0; jj < 8; ++jj) red[wv][jj][lane] = acc[jj];
      __syncthreads();
      for (int idx = tid; idx < 512; idx += 256) {
        int jj = idx >> 6, b = idx & 63;
        if (jj < nrows) {
          int n = n0 + jj;
          float v = red[0][jj][b] + red[1][jj][b] + red[2][jj][b] + red[3][jj][b];
          if (task < 128) a.corrT[(size_t)n * 64 + b] = v + a.corrB[n];
          else if (task < 256) a.pq[(size_t)b * H + n] = v;
          else if (task < 384) a.attH[(size_t)n * 64 + b] = v;
          else {
            float rv = v + a.rewB[n];
            a.rew[n * 64 + b] = rv;
            a.oR[((size_t)b * T + t) * 2 + n] = rv;
          }
        }
      }
      __syncthreads();
    }
    grid.sync();

    // ---- Phase D: energies ----
    {
      const int gw = bid * 4 + wv;
      for (int task = gw; task < 8192; task += NB * 4) {
        int b = task >> 7;
        const float* pkp = a.pk + (size_t)task * H;
        const float* qp = a.pq + (size_t)b * H;
        float acc = 0.f;
#pragma unroll
        for (int i = 0; i < 16; ++i) {
          int j = lane + i * 64;
          acc += tanhf(qp[j] + pkp[j]) * a.eW[j];
        }
#pragma unroll
        for (int off = 32; off > 0; off >>= 1) acc += __shfl_down(acc, off);
        if (lane == 0) a.energ[task] = acc;
      }
    }
    grid.sync();

    // ---- Phase E: softmax (redundant x4) + context ----
    for (int task = bid; task < 256; task += NB) {
      int b = task >> 2, kq = task & 3;
      float* se = &red[0][0][0];
      float* sa = se + 128;
      float* sv = se + 256;
      if (tid < 128) { float e = a.energ[b * 128 + tid]; se[tid] = e; sa[tid] = e; }
      __syncthreads();
      for (int st = 64; st > 0; st >>= 1) {
        if (tid < st) sa[tid] = fmaxf(sa[tid], sa[tid + st]);
        __syncthreads();
      }
      float mx = sa[0];
      __syncthreads();
      if (tid < 128) { float e2 = expf(se[tid] - mx); sa[tid] = e2; sv[tid] = e2; }
      __syncthreads();
      for (int st = 64; st > 0; st >>= 1) {
        if (tid < st) sv[tid] += sv[tid + st];
        __syncthreads();
      }
      float inv = 1.f / sv[0];
      __syncthreads();
      if (tid < 128) sa[tid] *= inv;
      __syncthreads();
      int k = kq * 256 + tid;
      const float* eb = a.enc + (size_t)b * S * KDIM + k;
      float accc = 0.f;
#pragma unroll 4
      for (int s2 = 0; s2 < 128; ++s2) accc = fmaf(sa[s2], eb[(size_t)s2 * KDIM], accc);
      a.ctx[(size_t)b * KDIM + k] = accc;
      if (kq == 0 && tid < 128) a.oA[((size_t)b * T + t) * S + tid] = sa[tid];
      __syncthreads();
    }
    grid.sync();

    // ---- Phase F: attv ctx-half GEMM + finalize ----
    for (int task = bid; task < 256; task += NB) {
      if (task < 128) {
        int n0 = task * 8;
        float acc[8] = {0.f,0.f,0.f,0.f,0.f,0.f,0.f,0.f};
        const float* arow = a.ctx + (size_t)lane * KDIM + wv * 256;
        const float* ws[8];
#pragma unroll
        for (int jj = 0; jj < 8; ++jj)
          ws[jj] = a.avW + (size_t)(n0 + jj) * 2048 + 1024 + wv * 256;
        dotN<8>(arow, ws, 8, acc);   // nsc=8: full 256-float window per wave (BUGFIX)
#pragma unroll
        for (int jj = 0; jj < 8; ++jj) red[wv][jj][lane] = acc[jj];
        __syncthreads();
        for (int idx = tid; idx < 512; idx += 256) {
          int jj = idx >> 6, b = idx & 63, n = n0 + jj;
          float v = red[0][jj][b] + red[1][jj][b] + red[2][jj][b] + red[3][jj][b]
                  + a.attH[(size_t)n * 64 + b] + a.avB[n];
          a.uv[(size_t)b * 2048 + 1024 + n] = tanhf(v);
        }
        __syncthreads();
      } else {
        int j0 = (task - 128) * 8;
        for (int idx = tid; idx < 512; idx += 256) {
          int jj = idx >> 6, b = idx & 63, j = j0 + jj;
          float r0 = a.rew[b], r1 = a.rew[64 + b];
          float cv = (r1 > r0) ? 0.f : tanhf(a.corrT[(size_t)j * 64 + b]);
          a.uv[(size_t)b * 2048 + j] = cv;
          a.oC[((size_t)b * T + t) * D + j] = cv;
        }
        __syncthreads();
      }
    }
    grid.sync();
  }
}

extern "C" void kernel_launch(void* const* d_in, const int* in_sizes, int n_in,
                              void* d_out, int out_size, void* d_ws, size_t ws_size,
                              hipStream_t stream) {
  const float* reversed_input = (const float*)d_in[0];
  const float* y_states = (const float*)d_in[3];
  const float* encoder = (const float*)d_in[4];
  const float* rnn_Wih = (const float*)d_in[6];
  const float* rnn_Whh = (const float*)d_in[7];
  const float* rnn_bih = (const float*)d_in[8];
  const float* rnn_bhh = (const float*)d_in[9];
  const float* out_Wih = (const float*)d_in[10];
  const float* out_Whh = (const float*)d_in[11];
  const float* out_bih = (const float*)d_in[12];
  const float* out_bhh = (const float*)d_in[13];
  const float* corr_W = (const float*)d_in[14];
  const float* corr_b = (const float*)d_in[15];
  const float* reward_W = (const float*)d_in[16];
  const float* reward_b = (const float*)d_in[17];
  const float* attv_W = (const float*)d_in[18];
  const float* attv_b = (const float*)d_in[19];
  const float* key_W = (const float*)d_in[20];
  const float* query_W = (const float*)d_in[21];
  const float* energy_W = (const float*)d_in[22];

  float* out_corrs = (float*)d_out;
  float* out_rewards = out_corrs + (size_t)B * T * D;
  float* out_attns = out_rewards + (size_t)B * T * 2;

  float* p = (float*)d_ws;
  float* rnn_flip = p;  p += (size_t)B * T * H;
  float* proj_keys = p; p += (size_t)B * S * H;
  float* hA = p;        p += (size_t)B * H;
  float* hB = p;        p += (size_t)B * H;
  float* uv = p;        p += (size_t)B * 2048;
  float* ctx = p;       p += (size_t)B * KDIM;
  float* pq = p;        p += (size_t)B * H;
  float* corrT = p;     p += (size_t)D * 64;
  float* attH = p;      p += (size_t)H * 64;
  float* rew = p;       p += 128;
  float* energ = p;     p += (size_t)B * S;
  size_t fixedF = (size_t)(p - (float*)d_ws);
  int CH = 8, chLog = 3;
  {
    int c = 128, l = 7;
    for (; c >= 8; c >>= 1, --l)
      if (ws_size >= (fixedF + (size_t)c * 64 * G3) * 4) break;
    if (c < 8) { c = 8; l = 3; }
    CH = c; chLog = l;
  }
  float* gibuf = p;

  int mp = 256;
  {
    hipDeviceProp_t prop;
    int dev = 0;
    if (hipGetDevice(&dev) == hipSuccess && hipGetDeviceProperties(&prop, dev) == hipSuccess)
      mp = prop.multiProcessorCount;
  }
  int ob1 = 0, ob2 = 0;
  if (hipOccupancyMaxActiveBlocksPerMultiprocessor(&ob1, (const void*)scan1_mega, 256, 0) != hipSuccess || ob1 < 1) ob1 = 1;
  if (hipOccupancyMaxActiveBlocksPerMultiprocessor(&ob2, (const void*)scan2_mega, 256, 0) != hipSuccess || ob2 < 1) ob2 = 1;
  int NB1 = ob1 * mp; if (NB1 > 512) NB1 = 512;
  int NB2 = ob2 * mp; if (NB2 > 512) NB2 = 512;

  dim3 blk(256);

  // proj_keys = encoder @ key_W^T
  gemm128<0><<<dim3(H / 128, (B * S) / 128), blk, 0, stream>>>(
      encoder, nullptr, KDIM, key_W, KDIM, nullptr, proj_keys, H, KDIM, 0, 0);

  // ---- scan 1 ----
  hipMemsetAsync(hA, 0, (size_t)B * H * sizeof(float), stream);
  for (int c0 = 0; c0 < T; c0 += CH) {
    gemm128<1><<<dim3(G3 / 128, (64 * CH) / 128), blk, 0, stream>>>(
        reversed_input, nullptr, 0, rnn_Wih, E, rnn_bih, gibuf, G3, E, c0, chLog);
    S1Args s1;
    s1.gi = gibuf; s1.Whh = rnn_Whh; s1.bhh = rnn_bhh;
    s1.hA = hA; s1.hB = hB; s1.flip = rnn_flip; s1.c0 = c0; s1.CH = CH;
    void* kp1[] = {&s1};
    hipLaunchCooperativeKernel((void*)scan1_mega, dim3(NB1), blk, kp1, 0, stream);
  }

  // ---- scan 2 ----
  hipMemsetAsync(hA, 0, (size_t)B * H * sizeof(float), stream);
  hipMemsetAsync(uv, 0, (size_t)B * 2048 * sizeof(float), stream);
  for (int c0 = 0; c0 < T; c0 += CH) {
    gemm128<2><<<dim3(G3 / 128, (64 * CH) / 128), blk, 0, stream>>>(
        y_states, rnn_flip, 0, out_Wih, 4096, out_bih, gibuf, G3, 2048, c0, chLog);
    S2Args s2;
    s2.gi = gibuf; s2.Wih = out_Wih; s2.Whh = out_Whh; s2.bhh = out_bhh;
    s2.corrW = corr_W; s2.corrB = corr_b; s2.rewW = reward_W; s2.rewB = reward_b;
    s2.qW = query_W; s2.avW = attv_W; s2.avB = attv_b; s2.eW = energy_W;
    s2.pk = proj_keys; s2.enc = encoder;
    s2.uv = uv; s2.hA = hA; s2.hB = hB; s2.ctx = ctx; s2.pq = pq;
    s2.corrT = corrT; s2.attH = attH; s2.rew = rew; s2.energ = energ;
    s2.oC = out_corrs; s2.oR = out_rewards; s2.oA = out_attns;
    s2.c0 = c0; s2.CH = CH;
    void* kp2[] = {&s2};
    hipLaunchCooperativeKernel((void*)scan2_mega, dim3(NB2), blk, kp2, 0, stream);
  }
}

// Round 6
// 57209.113 us; speedup vs baseline: 1.3073x; 1.3073x over previous
//
#include <hip/hip_runtime.h>
#include <hip/hip_bf16.h>
#include <math.h>

#define B 64
#define T 128
#define S 128
#define E 512
#define H 1024
#define D 1024
#define KDIM 1024
#define G3 3072
#define JT 16
#define NSTR 3074   // proj partial col stride: corr 0..1023 | rew 1024..1025 | pq 1026..2049 | attvh 2050..3073

__device__ __forceinline__ float sigmoidf_(float x) { return 1.f / (1.f + expf(-x)); }

// ---------------------------------------------------------------------------
// Scalar-broadcast skinny GEMM for M=64 (= B = one wave of lanes).
// Each block: one (seg, j-tile). 4 waves each own 128 contiguous k of the
// seg's 512-wide K window; W rows read at wave-uniform addresses. Partials
// written to part[seg][colOff + j][b]. (Proven in rounds 2-3.)
// ---------------------------------------------------------------------------
struct SBSeg { const float* A; const float* W; int lda; int ldw; int N; int colOff; };
struct SBArgs { SBSeg s[8]; };

__global__ __launch_bounds__(256) void sb_gemm(SBArgs args, int jtPerSeg, int Nstr,
                                               float* __restrict__ part) {
  const int seg = blockIdx.x / jtPerSeg;
  const int jt = blockIdx.x % jtPerSeg;
  const SBSeg sg = args.s[seg];
  const int j0 = jt * JT;
  if (j0 >= sg.N) return;
  const int wv = __builtin_amdgcn_readfirstlane(threadIdx.x >> 6);
  const int lane = threadIdx.x & 63;

  float a[128];
  const float4* ap = (const float4*)(sg.A + (size_t)lane * sg.lda + wv * 128);
#pragma unroll
  for (int q = 0; q < 32; ++q) {
    float4 v = ap[q];
    a[q * 4 + 0] = v.x; a[q * 4 + 1] = v.y; a[q * 4 + 2] = v.z; a[q * 4 + 3] = v.w;
  }
  float acc[JT];
#pragma unroll
  for (int jj = 0; jj < JT; ++jj) acc[jj] = 0.f;
#pragma unroll
  for (int jj = 0; jj < JT; ++jj) {
    int j = j0 + jj;
    if (j < sg.N) {
      const float4* wp = (const float4*)(sg.W + (size_t)j * sg.ldw + wv * 128);
      float s0 = 0.f, s1 = 0.f, s2 = 0.f, s3 = 0.f;
#pragma unroll
      for (int q = 0; q < 32; ++q) {
        float4 w4 = wp[q];
        s0 = fmaf(a[q * 4 + 0], w4.x, s0);
        s1 = fmaf(a[q * 4 + 1], w4.y, s1);
        s2 = fmaf(a[q * 4 + 2], w4.z, s2);
        s3 = fmaf(a[q * 4 + 3], w4.w, s3);
      }
      acc[jj] = (s0 + s1) + (s2 + s3);
    }
  }
  __shared__ float red[4][JT][64];
#pragma unroll
  for (int jj = 0; jj < JT; ++jj) red[wv][jj][lane] = acc[jj];
  __syncthreads();
  for (int idx = threadIdx.x; idx < JT * 64; idx += 256) {
    int jj = idx >> 6, b = idx & 63;
    int j = j0 + jj;
    if (j < sg.N) {
      float v = red[0][jj][b] + red[1][jj][b] + red[2][jj][b] + red[3][jj][b];
      part[((size_t)seg * Nstr + sg.colOff + j) * 64 + b] = v;
    }
  }
}

// ---------------------------------------------------------------------------
// GRU cell: gi = pre(biased, transposed [col][b]) + giPlanes partials;
// gh = bhh + gh partials. LDS transpose for the row-major h write
// (+ optional flipped copy, scan 1). Grid: 256 blocks. (Proven round 3.)
// ---------------------------------------------------------------------------
__global__ __launch_bounds__(256) void gru_reduce(
    const float* __restrict__ part, const float* __restrict__ pre_t,
    int giPlanes, int ghStart, int ghPlanes, const float* __restrict__ bhh,
    float* __restrict__ hrow, int hstride, float* __restrict__ flip_out, int t) {
  const int j0 = blockIdx.x * 4;
  const int jj = threadIdx.x >> 6;
  const int b = threadIdx.x & 63;
  const int j = j0 + jj;
  float gir = pre_t[(size_t)j * 64 + b];
  float giz = pre_t[(size_t)(H + j) * 64 + b];
  float gin = pre_t[(size_t)(2 * H + j) * 64 + b];
  for (int p2 = 0; p2 < giPlanes; ++p2) {
    const float* pp = part + (size_t)p2 * G3 * 64;
    gir += pp[(size_t)j * 64 + b];
    giz += pp[(size_t)(H + j) * 64 + b];
    gin += pp[(size_t)(2 * H + j) * 64 + b];
  }
  float ghr = bhh[j], ghz = bhh[H + j], ghn = bhh[2 * H + j];
  for (int p2 = ghStart; p2 < ghStart + ghPlanes; ++p2) {
    const float* pp = part + (size_t)p2 * G3 * 64;
    ghr += pp[(size_t)j * 64 + b];
    ghz += pp[(size_t)(H + j) * 64 + b];
    ghn += pp[(size_t)(2 * H + j) * 64 + b];
  }
  float r = sigmoidf_(gir + ghr);
  float z = sigmoidf_(giz + ghz);
  float n = tanhf(gin + r * ghn);
  float hold = hrow[(size_t)b * hstride + j];
  float hnew = (1.f - z) * n + z * hold;
  __shared__ float st[4][64];
  st[jj][b] = hnew;
  __syncthreads();
  int jl = threadIdx.x & 3, b2 = threadIdx.x >> 2;
  float v = st[jl][b2];
  hrow[(size_t)b2 * hstride + j0 + jl] = v;
  if (flip_out)
    flip_out[(size_t)b2 * T * H + (size_t)(T - 1 - t) * H + j0 + jl] = v;
}

// ---------------------------------------------------------------------------
// Fused attention: one block per b. Reduces pq from proj partials (planes 4,5),
// computes energies (wave per s), softmax, context, reward reduce + outputs.
// ---------------------------------------------------------------------------
__global__ __launch_bounds__(256) void attn_fused(
    const float* __restrict__ part, const float* __restrict__ pk,
    const float* __restrict__ eW, const float* __restrict__ enc,
    const float* __restrict__ reward_b,
    float* __restrict__ ctx, float* __restrict__ rewgate,
    float* __restrict__ out_rewards, float* __restrict__ out_attns, int t) {
  const int b = blockIdx.x;
  const int tid = threadIdx.x;
  const int wv = tid >> 6, lane = tid & 63;
  __shared__ float pqs[1024];
  __shared__ float al[128], tmp[128];
  __shared__ float rg[2];
  for (int j = tid; j < 1024; j += 256)
    pqs[j] = part[((size_t)4 * NSTR + 1026 + j) * 64 + b] +
             part[((size_t)5 * NSTR + 1026 + j) * 64 + b];
  if (tid < 2) {
    float rv = part[((size_t)2 * NSTR + 1024 + tid) * 64 + b] +
               part[((size_t)3 * NSTR + 1024 + tid) * 64 + b] + reward_b[tid];
    out_rewards[((size_t)b * T + t) * 2 + tid] = rv;
    rg[tid] = rv;
  }
  __syncthreads();
  // energies: wave wv handles s = wv, wv+4, ...
  for (int s = wv; s < S; s += 4) {
    const float* pkp = pk + ((size_t)b * S + s) * H;
    float acc = 0.f;
#pragma unroll
    for (int i = 0; i < 16; ++i) {
      int j = lane + i * 64;
      acc += tanhf(pqs[j] + pkp[j]) * eW[j];
    }
#pragma unroll
    for (int off = 32; off > 0; off >>= 1) acc += __shfl_down(acc, off);
    if (lane == 0) al[s] = acc;
  }
  __syncthreads();
  if (tid < 128) tmp[tid] = al[tid];
  __syncthreads();
  for (int st = 64; st > 0; st >>= 1) {
    if (tid < st) tmp[tid] = fmaxf(tmp[tid], tmp[tid + st]);
    __syncthreads();
  }
  float mx = tmp[0];
  __syncthreads();
  float e = 0.f;
  if (tid < 128) { e = expf(al[tid] - mx); tmp[tid] = e; }
  __syncthreads();
  for (int st = 64; st > 0; st >>= 1) {
    if (tid < st) tmp[tid] += tmp[tid + st];
    __syncthreads();
  }
  float inv = 1.f / tmp[0];
  __syncthreads();
  if (tid < 128) {
    float a2 = e * inv;
    al[tid] = a2;
    out_attns[((size_t)b * T + t) * S + tid] = a2;
  }
  __syncthreads();
  // context
  for (int k = tid; k < KDIM; k += 256) {
    const float* eb = enc + (size_t)b * S * KDIM + k;
    float acc = 0.f;
#pragma unroll 4
    for (int s2 = 0; s2 < S; ++s2) acc = fmaf(al[s2], eb[(size_t)s2 * KDIM], acc);
    ctx[(size_t)b * KDIM + k] = acc;
  }
  if (tid == 0) rewgate[b] = (rg[1] > rg[0]) ? 0.f : 1.f;
}

// ---------------------------------------------------------------------------
// Final: blocks 0..63: attv ctx-half full-K GEMM (16 cols/block) + h-half
// partials (planes 6,7) + bias + tanh -> uv[:,1024:]. Blocks 64..191: corr
// reduce (planes 0,1) + gate + tanh -> uv[:, :1024] + out_corrs.
// ---------------------------------------------------------------------------
__global__ __launch_bounds__(256) void final_kernel(
    const float* __restrict__ part, const float* __restrict__ avW,
    const float* __restrict__ avB, const float* __restrict__ corr_b,
    const float* __restrict__ ctx, const float* __restrict__ rewgate,
    float* __restrict__ uv, float* __restrict__ out_corrs, int t) {
  const int blk = blockIdx.x;
  const int tid = threadIdx.x;
  if (blk < 64) {
    const int wv = tid >> 6, lane = tid & 63;
    const int n0 = blk * 16;
    __shared__ float red[4][16][64];
    float acc[16];
#pragma unroll
    for (int jj = 0; jj < 16; ++jj) acc[jj] = 0.f;
    const float* arow = ctx + (size_t)lane * KDIM + wv * 256;
    for (int sc = 0; sc < 8; ++sc) {
      float av[32];
      const float4* ap = (const float4*)(arow + sc * 32);
#pragma unroll
      for (int q = 0; q < 8; ++q) {
        float4 v = ap[q];
        av[4*q] = v.x; av[4*q+1] = v.y; av[4*q+2] = v.z; av[4*q+3] = v.w;
      }
#pragma unroll
      for (int jj = 0; jj < 16; ++jj) {
        const float4* wp = (const float4*)(avW + (size_t)(n0 + jj) * 2048 + 1024 + wv * 256 + sc * 32);
        float s = acc[jj];
#pragma unroll
        for (int q = 0; q < 8; ++q) {
          float4 w = wp[q];
          s = fmaf(av[4*q],   w.x, s);
          s = fmaf(av[4*q+1], w.y, s);
          s = fmaf(av[4*q+2], w.z, s);
          s = fmaf(av[4*q+3], w.w, s);
        }
        acc[jj] = s;
      }
    }
#pragma unroll
    for (int jj = 0; jj < 16; ++jj) red[wv][jj][lane] = acc[jj];
    __syncthreads();
    for (int idx = tid; idx < 1024; idx += 256) {
      int jj = idx >> 6, bb = idx & 63;
      int n = n0 + jj;
      float v = red[0][jj][bb] + red[1][jj][bb] + red[2][jj][bb] + red[3][jj][bb]
              + part[((size_t)6 * NSTR + 2050 + n) * 64 + bb]
              + part[((size_t)7 * NSTR + 2050 + n) * 64 + bb] + avB[n];
      uv[(size_t)bb * 2048 + 1024 + n] = tanhf(v);
    }
  } else {
    const int j0 = (blk - 64) * 8;
    for (int idx = tid; idx < 512; idx += 256) {
      int jj = idx >> 6, bb = idx & 63;
      int j = j0 + jj;
      float v = part[((size_t)0 * NSTR + j) * 64 + bb] +
                part[((size_t)1 * NSTR + j) * 64 + bb] + corr_b[j];
      float cv = rewgate[bb] * tanhf(v);
      uv[(size_t)bb * 2048 + j] = cv;
      out_corrs[((size_t)bb * T + t) * D + j] = cv;
    }
  }
}

// ---------------------------------------------------------------------------
// Batched gi precompute (biased), transposed store pre[tloc][col][b].
// (Proven round 3.)
// ---------------------------------------------------------------------------
template<int KSEL>
__global__ __launch_bounds__(256) void gi_pre_kernel(
    const float* __restrict__ A1, const float* __restrict__ A2,
    const float* __restrict__ W, const float* __restrict__ bias,
    float* __restrict__ pre, int c0) {
  const int t = c0 + blockIdx.y;
  const int tloc = blockIdx.y;
  const int bn = blockIdx.x * 64;
  __shared__ __align__(16) float As[16][68];
  __shared__ __align__(16) float Ws[16][68];
  const int tid = threadIdx.x;
  const int tr = tid >> 4, tc = tid & 15;
  float acc[4][4];
#pragma unroll
  for (int i = 0; i < 4; ++i)
#pragma unroll
    for (int j = 0; j < 4; ++j) acc[i][j] = 0.f;
  const int Kd = KSEL ? 2048 : 512;
  const int ldw = KSEL ? 4096 : 512;
  for (int k0 = 0; k0 < Kd; k0 += 16) {
#pragma unroll
    for (int l = 0; l < 4; ++l) {
      int i = tid + l * 256;
      int r = i >> 4, kk = i & 15;
      float va;
      if (KSEL == 0) {
        va = A1[(size_t)r * (T * E) + (size_t)t * E + k0 + kk];
      } else {
        int k = k0 + kk;
        va = (k < 1024) ? A1[(size_t)r * (T * D) + (size_t)t * D + k]
                        : A2[(size_t)r * (T * H) + (size_t)t * H + (k - 1024)];
      }
      As[kk][r] = va;
    }
#pragma unroll
    for (int l = 0; l < 4; ++l) {
      int i = tid + l * 256;
      int c = i >> 4, kk = i & 15;
      Ws[kk][c] = W[(size_t)(bn + c) * ldw + k0 + kk];
    }
    __syncthreads();
#pragma unroll
    for (int kk = 0; kk < 16; ++kk) {
      float4 avv = *(const float4*)&As[kk][tr * 4];
      float4 wvv = *(const float4*)&Ws[kk][tc * 4];
      float aa[4] = {avv.x, avv.y, avv.z, avv.w};
      float ww[4] = {wvv.x, wvv.y, wvv.z, wvv.w};
#pragma unroll
      for (int i = 0; i < 4; ++i)
#pragma unroll
        for (int j = 0; j < 4; ++j)
          acc[i][j] = fmaf(aa[i], ww[j], acc[i][j]);
    }
    __syncthreads();
  }
  float* dst = pre + (size_t)tloc * G3 * 64;
#pragma unroll
  for (int i = 0; i < 4; ++i)
#pragma unroll
    for (int j = 0; j < 4; ++j) {
      int col = bn + tc * 4 + j;
      dst[(size_t)col * 64 + tr * 4 + i] = acc[i][j] + bias[col];
    }
}

// proj_keys = encoder @ key_W^T (row-major store), M=8192, N=1024, K=1024.
__global__ __launch_bounds__(256) void gemm_nt_big(
    const float* __restrict__ A, int sA, const float* __restrict__ W, int sW,
    float* __restrict__ C, int sC, int Kd) {
  __shared__ __align__(16) float As[16][68];
  __shared__ __align__(16) float Ws[16][68];
  const int bm = blockIdx.y * 64;
  const int bn = blockIdx.x * 64;
  const int tid = threadIdx.x;
  const int tr = tid >> 4, tc = tid & 15;
  float acc[4][4];
#pragma unroll
  for (int i = 0; i < 4; ++i)
#pragma unroll
    for (int j = 0; j < 4; ++j) acc[i][j] = 0.f;
  for (int k0 = 0; k0 < Kd; k0 += 16) {
#pragma unroll
    for (int l = 0; l < 4; ++l) {
      int i = tid + l * 256;
      int r = i >> 4, kk = i & 15;
      As[kk][r] = A[(size_t)(bm + r) * sA + k0 + kk];
    }
#pragma unroll
    for (int l = 0; l < 4; ++l) {
      int i = tid + l * 256;
      int c = i >> 4, kk = i & 15;
      Ws[kk][c] = W[(size_t)(bn + c) * sW + k0 + kk];
    }
    __syncthreads();
#pragma unroll
    for (int kk = 0; kk < 16; ++kk) {
      float4 avv = *(const float4*)&As[kk][tr * 4];
      float4 wvv = *(const float4*)&Ws[kk][tc * 4];
      float aa[4] = {avv.x, avv.y, avv.z, avv.w};
      float ww[4] = {wvv.x, wvv.y, wvv.z, wvv.w};
#pragma unroll
      for (int i = 0; i < 4; ++i)
#pragma unroll
        for (int j = 0; j < 4; ++j)
          acc[i][j] = fmaf(aa[i], ww[j], acc[i][j]);
    }
    __syncthreads();
  }
#pragma unroll
  for (int i = 0; i < 4; ++i)
#pragma unroll
    for (int j = 0; j < 4; ++j)
      C[(size_t)(bm + tr * 4 + i) * sC + bn + tc * 4 + j] = acc[i][j];
}

extern "C" void kernel_launch(void* const* d_in, const int* in_sizes, int n_in,
                              void* d_out, int out_size, void* d_ws, size_t ws_size,
                              hipStream_t stream) {
  const float* reversed_input = (const float*)d_in[0];
  const float* y_states = (const float*)d_in[3];
  const float* encoder = (const float*)d_in[4];
  const float* rnn_Wih = (const float*)d_in[6];
  const float* rnn_Whh = (const float*)d_in[7];
  const float* rnn_bih = (const float*)d_in[8];
  const float* rnn_bhh = (const float*)d_in[9];
  const float* out_Wih = (const float*)d_in[10];
  const float* out_Whh = (const float*)d_in[11];
  const float* out_bih = (const float*)d_in[12];
  const float* out_bhh = (const float*)d_in[13];
  const float* corr_W = (const float*)d_in[14];
  const float* corr_b = (const float*)d_in[15];
  const float* reward_W = (const float*)d_in[16];
  const float* reward_b = (const float*)d_in[17];
  const float* attv_W = (const float*)d_in[18];
  const float* attv_b = (const float*)d_in[19];
  const float* key_W = (const float*)d_in[20];
  const float* query_W = (const float*)d_in[21];
  const float* energy_W = (const float*)d_in[22];

  float* out_corrs = (float*)d_out;                    // (B,T,D)
  float* out_rewards = out_corrs + (size_t)B * T * D;  // (B,T,2)
  float* out_attns = out_rewards + (size_t)B * T * 2;  // (B,T,S)

  // workspace layout (floats)
  float* p = (float*)d_ws;
  float* rnn_flip = p;  p += (size_t)B * T * H;        // 33.5 MB
  float* proj_keys = p; p += (size_t)B * S * H;        // 33.5 MB
  float* part = p;      p += (size_t)8 * NSTR * 64;    // 6.3 MB partial planes
  float* h = p;         p += (size_t)B * H;            // GRU state (both scans)
  float* uv = p;        p += (size_t)B * 2048;         // [corr | att] row-major
  float* ctx = p;       p += (size_t)B * KDIM;
  float* rewgate = p;   p += 64;
  size_t fixedF = (size_t)(p - (float*)d_ws);
  const size_t perT = (size_t)G3 * 64;
  int CH = 8;
  if (ws_size >= (fixedF + 32ull * perT) * 4) CH = 32;        // cap 32 (L3 friendliness)
  else if (ws_size >= (fixedF + 16ull * perT) * 4) CH = 16;
  float* gibuf = p;  // CH * G3 * 64 floats

  hipMemsetAsync(h, 0, (size_t)B * H * sizeof(float), stream);
  hipMemsetAsync(uv, 0, (size_t)B * 2048 * sizeof(float), stream);

  dim3 blk(256);

  // proj_keys = encoder @ key_W^T
  gemm_nt_big<<<dim3(H / 64, (B * S) / 64), blk, 0, stream>>>(
      encoder, KDIM, key_W, KDIM, proj_keys, H, KDIM);

  // ---- scan 1: backward GRU ----
  for (int c0 = 0; c0 < T; c0 += CH) {
    gi_pre_kernel<0><<<dim3(G3 / 64, CH), blk, 0, stream>>>(
        reversed_input, nullptr, rnn_Wih, rnn_bih, gibuf, c0);
    for (int tl = 0; tl < CH; ++tl) {
      int t = c0 + tl;
      SBArgs s1{};
      s1.s[0] = { h, rnn_Whh, H, H, G3, 0 };
      s1.s[1] = { h + 512, rnn_Whh + 512, H, H, G3, 0 };
      sb_gemm<<<2 * 192, blk, 0, stream>>>(s1, 192, G3, part);
      gru_reduce<<<256, blk, 0, stream>>>(part, gibuf + (size_t)tl * perT,
                                          0, 0, 2, rnn_bhh, h, H, rnn_flip, t);
    }
  }

  // ---- scan 2: output GRU + attention ----
  hipMemsetAsync(h, 0, (size_t)B * H * sizeof(float), stream);
  for (int c0 = 0; c0 < T; c0 += CH) {
    gi_pre_kernel<1><<<dim3(G3 / 64, CH), blk, 0, stream>>>(
        y_states, rnn_flip, out_Wih, out_bih, gibuf, c0);
    for (int tl = 0; tl < CH; ++tl) {
      int t = c0 + tl;
      // 1) gates GEMM: gi(uv, K=2048) + gh(h, K=1024), 6 K-segments
      SBArgs k1{};
      for (int s2 = 0; s2 < 4; ++s2)
        k1.s[s2] = { uv + s2 * 512, out_Wih + 2048 + s2 * 512, 2048, 4096, G3, 0 };
      for (int s2 = 0; s2 < 2; ++s2)
        k1.s[4 + s2] = { h + s2 * 512, out_Whh + s2 * 512, H, H, G3, 0 };
      sb_gemm<<<6 * 192, blk, 0, stream>>>(k1, 192, G3, part);
      // 2) GRU cell
      gru_reduce<<<256, blk, 0, stream>>>(part, gibuf + (size_t)tl * perT,
                                          4, 4, 2, out_bhh, h, H, nullptr, t);
      // 3) h-projections: corr | reward | query | attv_h (8 K-segments)
      SBArgs hp{};
      hp.s[0] = { h, corr_W, H, H, 1024, 0 };
      hp.s[1] = { h + 512, corr_W + 512, H, H, 1024, 0 };
      hp.s[2] = { h, reward_W, H, H, 2, 1024 };
      hp.s[3] = { h + 512, reward_W + 512, H, H, 2, 1024 };
      hp.s[4] = { h, query_W, H, H, 1024, 1026 };
      hp.s[5] = { h + 512, query_W + 512, H, H, 1024, 1026 };
      hp.s[6] = { h, attv_W, H, 2048, 1024, 2050 };
      hp.s[7] = { h + 512, attv_W + 512, H, 2048, 1024, 2050 };
      sb_gemm<<<8 * 64, blk, 0, stream>>>(hp, 64, NSTR, part);
      // 4) fused attention (pq reduce + energies + softmax + context + reward)
      attn_fused<<<64, blk, 0, stream>>>(part, proj_keys, energy_W, encoder,
                                         reward_b, ctx, rewgate,
                                         out_rewards, out_attns, t);
      // 5) attv ctx-half + combine + corr finalize
      final_kernel<<<192, blk, 0, stream>>>(part, attv_W, attv_b, corr_b, ctx,
                                            rewgate, uv, out_corrs, t);
    }
  }
}

// Round 7
// 42228.619 us; speedup vs baseline: 1.7710x; 1.3547x over previous
//
#include <hip/hip_runtime.h>
#include <hip/hip_bf16.h>
#include <math.h>

#define B 64
#define T 128
#define S 128
#define E 512
#define H 1024
#define D 1024
#define KDIM 1024
#define G3 3072
#define JT 16
#define NSTR 3074   // hp partial cols: corr 0..1023 | rew 1024..1025 | pq 1026..2049 | attvh 2050..3073

__device__ __forceinline__ float sigmoidf_(float x) { return 1.f / (1.f + expf(-x)); }

// ---------------------------------------------------------------------------
// Scan-1 fused gh-GEMM + GRU. Grid 256 x 512 thr. Block owns 4 j-columns;
// 8 waves cover K=1024 in two 64-float windows each; LDS reduce; GRU in-block.
// ---------------------------------------------------------------------------
__global__ __launch_bounds__(512) void fused_gates1(
    const float* __restrict__ gi, const float* __restrict__ Whh,
    const float* __restrict__ bhh, const float* __restrict__ hprev,
    float* __restrict__ hcur, float* __restrict__ flip, int t) {
  const int j0 = blockIdx.x * 4;
  const int tid = threadIdx.x;
  const int wv = tid >> 6, lane = tid & 63;
  __shared__ float red[8][12][64];
  __shared__ float st[4][64];
  float acc[12];
#pragma unroll
  for (int r = 0; r < 12; ++r) acc[r] = 0.f;
  for (int p = 0; p < 2; ++p) {
    const int k0 = (p * 8 + wv) * 64;
    float av[64];
    const float4* ap = (const float4*)(hprev + (size_t)lane * H + k0);
#pragma unroll
    for (int q = 0; q < 16; ++q) {
      float4 v = ap[q];
      av[4*q] = v.x; av[4*q+1] = v.y; av[4*q+2] = v.z; av[4*q+3] = v.w;
    }
#pragma unroll
    for (int jj = 0; jj < 4; ++jj)
#pragma unroll
      for (int g = 0; g < 3; ++g) {
        const float4* wp = (const float4*)(Whh + (size_t)(g * H + j0 + jj) * H + k0);
        float s = acc[jj * 3 + g];
#pragma unroll
        for (int q = 0; q < 16; ++q) {
          float4 w = wp[q];
          s = fmaf(av[4*q],   w.x, s);
          s = fmaf(av[4*q+1], w.y, s);
          s = fmaf(av[4*q+2], w.z, s);
          s = fmaf(av[4*q+3], w.w, s);
        }
        acc[jj * 3 + g] = s;
      }
  }
#pragma unroll
  for (int r = 0; r < 12; ++r) red[wv][r][lane] = acc[r];
  __syncthreads();
  if (tid < 256) {
    const int jj = tid >> 6, b = tid & 63, j = j0 + jj;
    float ghr = bhh[j], ghz = bhh[H + j], ghn = bhh[2 * H + j];
#pragma unroll
    for (int w = 0; w < 8; ++w) {
      ghr += red[w][jj * 3 + 0][b];
      ghz += red[w][jj * 3 + 1][b];
      ghn += red[w][jj * 3 + 2][b];
    }
    float gir = gi[(size_t)j * 64 + b];
    float giz = gi[(size_t)(H + j) * 64 + b];
    float gin = gi[(size_t)(2 * H + j) * 64 + b];
    float r = sigmoidf_(gir + ghr);
    float z = sigmoidf_(giz + ghz);
    float n = tanhf(gin + r * ghn);
    float hnew = (1.f - z) * n + z * hprev[(size_t)b * H + j];
    st[jj][b] = hnew;
  }
  __syncthreads();
  if (tid < 256) {
    const int jl = tid & 3, b2 = tid >> 2;
    float v = st[jl][b2];
    hcur[(size_t)b2 * H + j0 + jl] = v;
    flip[(size_t)b2 * T * H + (size_t)(T - 1 - t) * H + j0 + jl] = v;
  }
}

// ---------------------------------------------------------------------------
// Scan-2 fused gates GEMM (uv K=2048 + h K=1024) + GRU. Grid 256 x 512 thr.
// Acc rows per j: 0=r(uv+h) 1=z(uv+h) 2=n_uv 3=n_h (kept separate for GRU).
// ---------------------------------------------------------------------------
__global__ __launch_bounds__(512) void fused_gates2(
    const float* __restrict__ gi, const float* __restrict__ Wih,
    const float* __restrict__ Whh, const float* __restrict__ bhh,
    const float* __restrict__ uv, const float* __restrict__ hprev,
    float* __restrict__ hcur) {
  const int j0 = blockIdx.x * 4;
  const int tid = threadIdx.x;
  const int wv = tid >> 6, lane = tid & 63;
  __shared__ float red[8][16][64];
  __shared__ float st[4][64];
  float acc[16];
#pragma unroll
  for (int r = 0; r < 16; ++r) acc[r] = 0.f;
  for (int p = 0; p < 6; ++p) {
    const float* arow;
    int k0;
    if (p < 4) { k0 = (p * 8 + wv) * 64; arow = uv + (size_t)lane * 2048 + k0; }
    else       { k0 = ((p - 4) * 8 + wv) * 64; arow = hprev + (size_t)lane * H + k0; }
    float av[64];
    const float4* ap = (const float4*)arow;
#pragma unroll
    for (int q = 0; q < 16; ++q) {
      float4 v = ap[q];
      av[4*q] = v.x; av[4*q+1] = v.y; av[4*q+2] = v.z; av[4*q+3] = v.w;
    }
#pragma unroll
    for (int jj = 0; jj < 4; ++jj)
#pragma unroll
      for (int g = 0; g < 3; ++g) {
        const float4* wp;
        int r;
        if (p < 4) { wp = (const float4*)(Wih + (size_t)(g * H + j0 + jj) * 4096 + 2048 + k0); r = jj * 4 + g; }
        else       { wp = (const float4*)(Whh + (size_t)(g * H + j0 + jj) * H + k0); r = jj * 4 + ((g == 2) ? 3 : g); }
        float s = acc[r];
#pragma unroll
        for (int q = 0; q < 16; ++q) {
          float4 w = wp[q];
          s = fmaf(av[4*q],   w.x, s);
          s = fmaf(av[4*q+1], w.y, s);
          s = fmaf(av[4*q+2], w.z, s);
          s = fmaf(av[4*q+3], w.w, s);
        }
        acc[r] = s;
      }
  }
#pragma unroll
  for (int r = 0; r < 16; ++r) red[wv][r][lane] = acc[r];
  __syncthreads();
  if (tid < 256) {
    const int jj = tid >> 6, b = tid & 63, j = j0 + jj;
    float s0 = 0.f, s1 = 0.f, s2 = 0.f, s3 = 0.f;
#pragma unroll
    for (int w = 0; w < 8; ++w) {
      s0 += red[w][jj * 4 + 0][b];
      s1 += red[w][jj * 4 + 1][b];
      s2 += red[w][jj * 4 + 2][b];
      s3 += red[w][jj * 4 + 3][b];
    }
    float gir = gi[(size_t)j * 64 + b];
    float giz = gi[(size_t)(H + j) * 64 + b];
    float gin = gi[(size_t)(2 * H + j) * 64 + b];
    float r = sigmoidf_(gir + s0 + bhh[j]);
    float z = sigmoidf_(giz + s1 + bhh[H + j]);
    float n = tanhf(gin + s2 + r * (s3 + bhh[2 * H + j]));
    float hnew = (1.f - z) * n + z * hprev[(size_t)b * H + j];
    st[jj][b] = hnew;
  }
  __syncthreads();
  if (tid < 256) {
    const int jl = tid & 3, b2 = tid >> 2;
    hcur[(size_t)b2 * H + j0 + jl] = st[jl][b2];
  }
}

// ---------------------------------------------------------------------------
// Scalar-broadcast skinny GEMM (proven rounds 2-6): partials to part planes.
// ---------------------------------------------------------------------------
struct SBSeg { const float* A; const float* W; int lda; int ldw; int N; int colOff; };
struct SBArgs { SBSeg s[8]; };

__global__ __launch_bounds__(256) void sb_gemm(SBArgs args, int jtPerSeg, int Nstr,
                                               float* __restrict__ part) {
  const int seg = blockIdx.x / jtPerSeg;
  const int jt = blockIdx.x % jtPerSeg;
  const SBSeg sg = args.s[seg];
  const int j0 = jt * JT;
  if (j0 >= sg.N) return;
  const int wv = __builtin_amdgcn_readfirstlane(threadIdx.x >> 6);
  const int lane = threadIdx.x & 63;
  float a[128];
  const float4* ap = (const float4*)(sg.A + (size_t)lane * sg.lda + wv * 128);
#pragma unroll
  for (int q = 0; q < 32; ++q) {
    float4 v = ap[q];
    a[q * 4 + 0] = v.x; a[q * 4 + 1] = v.y; a[q * 4 + 2] = v.z; a[q * 4 + 3] = v.w;
  }
  float acc[JT];
#pragma unroll
  for (int jj = 0; jj < JT; ++jj) acc[jj] = 0.f;
#pragma unroll
  for (int jj = 0; jj < JT; ++jj) {
    int j = j0 + jj;
    if (j < sg.N) {
      const float4* wp = (const float4*)(sg.W + (size_t)j * sg.ldw + wv * 128);
      float s0 = 0.f, s1 = 0.f, s2 = 0.f, s3 = 0.f;
#pragma unroll
      for (int q = 0; q < 32; ++q) {
        float4 w4 = wp[q];
        s0 = fmaf(a[q * 4 + 0], w4.x, s0);
        s1 = fmaf(a[q * 4 + 1], w4.y, s1);
        s2 = fmaf(a[q * 4 + 2], w4.z, s2);
        s3 = fmaf(a[q * 4 + 3], w4.w, s3);
      }
      acc[jj] = (s0 + s1) + (s2 + s3);
    }
  }
  __shared__ float red[4][JT][64];
#pragma unroll
  for (int jj = 0; jj < JT; ++jj) red[wv][jj][lane] = acc[jj];
  __syncthreads();
  for (int idx = threadIdx.x; idx < JT * 64; idx += 256) {
    int jj = idx >> 6, b = idx & 63;
    int j = j0 + jj;
    if (j < sg.N) {
      float v = red[0][jj][b] + red[1][jj][b] + red[2][jj][b] + red[3][jj][b];
      part[((size_t)seg * Nstr + sg.colOff + j) * 64 + b] = v;
    }
  }
}

// ---------------------------------------------------------------------------
// Fused attention: one block (1024 thr, 16 waves) per b. pq reduce, energies,
// softmax, reward+gate, corr finalize (+outputs), context.
// ---------------------------------------------------------------------------
__global__ __launch_bounds__(1024) void attn_fused(
    const float* __restrict__ part, const float* __restrict__ pk,
    const float* __restrict__ eW, const float* __restrict__ enc,
    const float* __restrict__ reward_b, const float* __restrict__ corr_b,
    float* __restrict__ ctx, float* __restrict__ uv,
    float* __restrict__ out_rewards, float* __restrict__ out_attns,
    float* __restrict__ out_corrs, int t) {
  const int b = blockIdx.x;
  const int tid = threadIdx.x;
  const int wv = tid >> 6, lane = tid & 63;
  __shared__ float pqs[1024];
  __shared__ float al[128], tmp[128];
  __shared__ float rv2[2];
  pqs[tid] = part[((size_t)4 * NSTR + 1026 + tid) * 64 + b] +
             part[((size_t)5 * NSTR + 1026 + tid) * 64 + b];
  if (tid < 2) {
    float rv = part[((size_t)2 * NSTR + 1024 + tid) * 64 + b] +
               part[((size_t)3 * NSTR + 1024 + tid) * 64 + b] + reward_b[tid];
    out_rewards[((size_t)b * T + t) * 2 + tid] = rv;
    rv2[tid] = rv;
  }
  __syncthreads();
  // energies: 16 waves x 8 s each
#pragma unroll
  for (int i = 0; i < 8; ++i) {
    int s = wv + i * 16;
    const float* pkp = pk + ((size_t)b * S + s) * H;
    float acc = 0.f;
#pragma unroll
    for (int q = 0; q < 16; ++q) {
      int j = lane + q * 64;
      acc += tanhf(pqs[j] + pkp[j]) * eW[j];
    }
#pragma unroll
    for (int off = 32; off > 0; off >>= 1) acc += __shfl_down(acc, off);
    if (lane == 0) al[s] = acc;
  }
  __syncthreads();
  if (tid < 128) tmp[tid] = al[tid];
  __syncthreads();
  for (int st = 64; st > 0; st >>= 1) {
    if (tid < st) tmp[tid] = fmaxf(tmp[tid], tmp[tid + st]);
    __syncthreads();
  }
  float mx = tmp[0];
  __syncthreads();
  float e = 0.f;
  if (tid < 128) { e = expf(al[tid] - mx); tmp[tid] = e; }
  __syncthreads();
  for (int st = 64; st > 0; st >>= 1) {
    if (tid < st) tmp[tid] += tmp[tid + st];
    __syncthreads();
  }
  float inv = 1.f / tmp[0];
  __syncthreads();
  if (tid < 128) {
    float a2 = e * inv;
    al[tid] = a2;
    out_attns[((size_t)b * T + t) * S + tid] = a2;
  }
  __syncthreads();
  // corr finalize (gated) — j = tid
  float g = (rv2[1] > rv2[0]) ? 0.f : 1.f;
  {
    float v = part[((size_t)0 * NSTR + tid) * 64 + b] +
              part[((size_t)1 * NSTR + tid) * 64 + b] + corr_b[tid];
    float cv = g * tanhf(v);
    uv[(size_t)b * 2048 + tid] = cv;
    out_corrs[((size_t)b * T + t) * D + tid] = cv;
  }
  // context — k = tid
  {
    const float* eb = enc + (size_t)b * S * KDIM + tid;
    float acc = 0.f;
#pragma unroll 8
    for (int s2 = 0; s2 < S; ++s2) acc = fmaf(al[s2], eb[(size_t)s2 * KDIM], acc);
    ctx[(size_t)b * KDIM + tid] = acc;
  }
}

// ---------------------------------------------------------------------------
// attv ctx-half GEMM + combine + tanh -> uv att-half. Grid 128 x 256 thr.
// ---------------------------------------------------------------------------
__global__ __launch_bounds__(256) void final_attv(
    const float* __restrict__ part, const float* __restrict__ avW,
    const float* __restrict__ avB, const float* __restrict__ ctx,
    float* __restrict__ uv) {
  const int n0 = blockIdx.x * 8;
  const int tid = threadIdx.x;
  const int wv = tid >> 6, lane = tid & 63;
  __shared__ float red[4][8][64];
  float acc[8];
#pragma unroll
  for (int jj = 0; jj < 8; ++jj) acc[jj] = 0.f;
  for (int p = 0; p < 2; ++p) {
    const int k0 = (p * 4 + wv) * 128;
    float av[128];
    const float4* ap = (const float4*)(ctx + (size_t)lane * KDIM + k0);
#pragma unroll
    for (int q = 0; q < 32; ++q) {
      float4 v = ap[q];
      av[4*q] = v.x; av[4*q+1] = v.y; av[4*q+2] = v.z; av[4*q+3] = v.w;
    }
#pragma unroll
    for (int jj = 0; jj < 8; ++jj) {
      const float4* wp = (const float4*)(avW + (size_t)(n0 + jj) * 2048 + 1024 + k0);
      float s = acc[jj];
#pragma unroll
      for (int q = 0; q < 32; ++q) {
        float4 w = wp[q];
        s = fmaf(av[4*q],   w.x, s);
        s = fmaf(av[4*q+1], w.y, s);
        s = fmaf(av[4*q+2], w.z, s);
        s = fmaf(av[4*q+3], w.w, s);
      }
      acc[jj] = s;
    }
  }
#pragma unroll
  for (int jj = 0; jj < 8; ++jj) red[wv][jj][lane] = acc[jj];
  __syncthreads();
  for (int idx = tid; idx < 512; idx += 256) {
    int jj = idx >> 6, bb = idx & 63;
    int n = n0 + jj;
    float v = red[0][jj][bb] + red[1][jj][bb] + red[2][jj][bb] + red[3][jj][bb]
            + part[((size_t)6 * NSTR + 2050 + n) * 64 + bb]
            + part[((size_t)7 * NSTR + 2050 + n) * 64 + bb] + avB[n];
    uv[(size_t)bb * 2048 + 1024 + n] = tanhf(v);
  }
}

// ---------------------------------------------------------------------------
// Batched gi precompute (biased), transposed store pre[tloc][col][b]. (Proven.)
// ---------------------------------------------------------------------------
template<int KSEL>
__global__ __launch_bounds__(256) void gi_pre_kernel(
    const float* __restrict__ A1, const float* __restrict__ A2,
    const float* __restrict__ W, const float* __restrict__ bias,
    float* __restrict__ pre, int c0) {
  const int t = c0 + blockIdx.y;
  const int tloc = blockIdx.y;
  const int bn = blockIdx.x * 64;
  __shared__ __align__(16) float As[16][68];
  __shared__ __align__(16) float Ws[16][68];
  const int tid = threadIdx.x;
  const int tr = tid >> 4, tc = tid & 15;
  float acc[4][4];
#pragma unroll
  for (int i = 0; i < 4; ++i)
#pragma unroll
    for (int j = 0; j < 4; ++j) acc[i][j] = 0.f;
  const int Kd = KSEL ? 2048 : 512;
  const int ldw = KSEL ? 4096 : 512;
  for (int k0 = 0; k0 < Kd; k0 += 16) {
#pragma unroll
    for (int l = 0; l < 4; ++l) {
      int i = tid + l * 256;
      int r = i >> 4, kk = i & 15;
      float va;
      if (KSEL == 0) {
        va = A1[(size_t)r * (T * E) + (size_t)t * E + k0 + kk];
      } else {
        int k = k0 + kk;
        va = (k < 1024) ? A1[(size_t)r * (T * D) + (size_t)t * D + k]
                        : A2[(size_t)r * (T * H) + (size_t)t * H + (k - 1024)];
      }
      As[kk][r] = va;
    }
#pragma unroll
    for (int l = 0; l < 4; ++l) {
      int i = tid + l * 256;
      int c = i >> 4, kk = i & 15;
      Ws[kk][c] = W[(size_t)(bn + c) * ldw + k0 + kk];
    }
    __syncthreads();
#pragma unroll
    for (int kk = 0; kk < 16; ++kk) {
      float4 avv = *(const float4*)&As[kk][tr * 4];
      float4 wvv = *(const float4*)&Ws[kk][tc * 4];
      float aa[4] = {avv.x, avv.y, avv.z, avv.w};
      float ww[4] = {wvv.x, wvv.y, wvv.z, wvv.w};
#pragma unroll
      for (int i = 0; i < 4; ++i)
#pragma unroll
        for (int j = 0; j < 4; ++j)
          acc[i][j] = fmaf(aa[i], ww[j], acc[i][j]);
    }
    __syncthreads();
  }
  float* dst = pre + (size_t)tloc * G3 * 64;
#pragma unroll
  for (int i = 0; i < 4; ++i)
#pragma unroll
    for (int j = 0; j < 4; ++j) {
      int col = bn + tc * 4 + j;
      dst[(size_t)col * 64 + tr * 4 + i] = acc[i][j] + bias[col];
    }
}

// proj_keys = encoder @ key_W^T, M=8192, N=1024, K=1024. (Proven.)
__global__ __launch_bounds__(256) void gemm_nt_big(
    const float* __restrict__ A, int sA, const float* __restrict__ W, int sW,
    float* __restrict__ C, int sC, int Kd) {
  __shared__ __align__(16) float As[16][68];
  __shared__ __align__(16) float Ws[16][68];
  const int bm = blockIdx.y * 64;
  const int bn = blockIdx.x * 64;
  const int tid = threadIdx.x;
  const int tr = tid >> 4, tc = tid & 15;
  float acc[4][4];
#pragma unroll
  for (int i = 0; i < 4; ++i)
#pragma unroll
    for (int j = 0; j < 4; ++j) acc[i][j] = 0.f;
  for (int k0 = 0; k0 < Kd; k0 += 16) {
#pragma unroll
    for (int l = 0; l < 4; ++l) {
      int i = tid + l * 256;
      int r = i >> 4, kk = i & 15;
      As[kk][r] = A[(size_t)(bm + r) * sA + k0 + kk];
    }
#pragma unroll
    for (int l = 0; l < 4; ++l) {
      int i = tid + l * 256;
      int c = i >> 4, kk = i & 15;
      Ws[kk][c] = W[(size_t)(bn + c) * sW + k0 + kk];
    }
    __syncthreads();
#pragma unroll
    for (int kk = 0; kk < 16; ++kk) {
      float4 avv = *(const float4*)&As[kk][tr * 4];
      float4 wvv = *(const float4*)&Ws[kk][tc * 4];
      float aa[4] = {avv.x, avv.y, avv.z, avv.w};
      float ww[4] = {wvv.x, wvv.y, wvv.z, wvv.w};
#pragma unroll
      for (int i = 0; i < 4; ++i)
#pragma unroll
        for (int j = 0; j < 4; ++j)
          acc[i][j] = fmaf(aa[i], ww[j], acc[i][j]);
    }
    __syncthreads();
  }
#pragma unroll
  for (int i = 0; i < 4; ++i)
#pragma unroll
    for (int j = 0; j < 4; ++j)
      C[(size_t)(bm + tr * 4 + i) * sC + bn + tc * 4 + j] = acc[i][j];
}

extern "C" void kernel_launch(void* const* d_in, const int* in_sizes, int n_in,
                              void* d_out, int out_size, void* d_ws, size_t ws_size,
                              hipStream_t stream) {
  const float* reversed_input = (const float*)d_in[0];
  const float* y_states = (const float*)d_in[3];
  const float* encoder = (const float*)d_in[4];
  const float* rnn_Wih = (const float*)d_in[6];
  const float* rnn_Whh = (const float*)d_in[7];
  const float* rnn_bih = (const float*)d_in[8];
  const float* rnn_bhh = (const float*)d_in[9];
  const float* out_Wih = (const float*)d_in[10];
  const float* out_Whh = (const float*)d_in[11];
  const float* out_bih = (const float*)d_in[12];
  const float* out_bhh = (const float*)d_in[13];
  const float* corr_W = (const float*)d_in[14];
  const float* corr_b = (const float*)d_in[15];
  const float* reward_W = (const float*)d_in[16];
  const float* reward_b = (const float*)d_in[17];
  const float* attv_W = (const float*)d_in[18];
  const float* attv_b = (const float*)d_in[19];
  const float* key_W = (const float*)d_in[20];
  const float* query_W = (const float*)d_in[21];
  const float* energy_W = (const float*)d_in[22];

  float* out_corrs = (float*)d_out;                    // (B,T,D)
  float* out_rewards = out_corrs + (size_t)B * T * D;  // (B,T,2)
  float* out_attns = out_rewards + (size_t)B * T * 2;  // (B,T,S)

  // workspace (floats)
  float* p = (float*)d_ws;
  float* rnn_flip = p;  p += (size_t)B * T * H;
  float* proj_keys = p; p += (size_t)B * S * H;
  float* part = p;      p += (size_t)8 * NSTR * 64;
  float* hA = p;        p += (size_t)B * H;
  float* hB = p;        p += (size_t)B * H;
  float* uv = p;        p += (size_t)B * 2048;
  float* ctx = p;       p += (size_t)B * KDIM;
  size_t fixedF = (size_t)(p - (float*)d_ws);
  const size_t perT = (size_t)G3 * 64;
  int CH = 8;
  if (ws_size >= (fixedF + 64ull * perT) * 4) CH = 64;
  else if (ws_size >= (fixedF + 32ull * perT) * 4) CH = 32;
  else if (ws_size >= (fixedF + 16ull * perT) * 4) CH = 16;
  float* gibuf = p;  // CH * G3 * 64 floats

  dim3 blk256(256), blk512(512), blk1024(1024);

  // proj_keys = encoder @ key_W^T
  gemm_nt_big<<<dim3(H / 64, (B * S) / 64), blk256, 0, stream>>>(
      encoder, KDIM, key_W, KDIM, proj_keys, H, KDIM);

  // ---- scan 1: backward GRU (1 launch/step) ----
  hipMemsetAsync(hA, 0, (size_t)B * H * sizeof(float), stream);
  for (int c0 = 0; c0 < T; c0 += CH) {
    gi_pre_kernel<0><<<dim3(G3 / 64, CH), blk256, 0, stream>>>(
        reversed_input, nullptr, rnn_Wih, rnn_bih, gibuf, c0);
    for (int tl = 0; tl < CH; ++tl) {
      int t = c0 + tl;
      const float* hp_ = (t & 1) ? hB : hA;
      float* hc_ = (t & 1) ? hA : hB;
      fused_gates1<<<256, blk512, 0, stream>>>(
          gibuf + (size_t)tl * perT, rnn_Whh, rnn_bhh, hp_, hc_, rnn_flip, t);
    }
  }

  // ---- scan 2: output GRU + attention (4 launches/step) ----
  hipMemsetAsync(hA, 0, (size_t)B * H * sizeof(float), stream);
  hipMemsetAsync(uv, 0, (size_t)B * 2048 * sizeof(float), stream);
  for (int c0 = 0; c0 < T; c0 += CH) {
    gi_pre_kernel<1><<<dim3(G3 / 64, CH), blk256, 0, stream>>>(
        y_states, rnn_flip, out_Wih, out_bih, gibuf, c0);
    for (int tl = 0; tl < CH; ++tl) {
      int t = c0 + tl;
      const float* hp_ = (t & 1) ? hB : hA;
      float* hc_ = (t & 1) ? hA : hB;
      // 1) gates GEMM + GRU
      fused_gates2<<<256, blk512, 0, stream>>>(
          gibuf + (size_t)tl * perT, out_Wih, out_Whh, out_bhh, uv, hp_, hc_);
      // 2) h-projections: corr | reward | query | attv_h
      SBArgs hpj{};
      hpj.s[0] = { hc_, corr_W, H, H, 1024, 0 };
      hpj.s[1] = { hc_ + 512, corr_W + 512, H, H, 1024, 0 };
      hpj.s[2] = { hc_, reward_W, H, H, 2, 1024 };
      hpj.s[3] = { hc_ + 512, reward_W + 512, H, H, 2, 1024 };
      hpj.s[4] = { hc_, query_W, H, H, 1024, 1026 };
      hpj.s[5] = { hc_ + 512, query_W + 512, H, H, 1024, 1026 };
      hpj.s[6] = { hc_, attv_W, H, 2048, 1024, 2050 };
      hpj.s[7] = { hc_ + 512, attv_W + 512, H, 2048, 1024, 2050 };
      sb_gemm<<<8 * 64, blk256, 0, stream>>>(hpj, 64, NSTR, part);
      // 3) fused attention + reward gate + corr finalize + context
      attn_fused<<<64, blk1024, 0, stream>>>(part, proj_keys, energy_W, encoder,
                                             reward_b, corr_b, ctx, uv,
                                             out_rewards, out_attns, out_corrs, t);
      // 4) attv ctx-half + combine -> uv att-half
      final_attv<<<128, blk256, 0, stream>>>(part, attv_W, attv_b, ctx, uv);
    }
  }
}

// Round 8
// 24133.885 us; speedup vs baseline: 3.0988x; 1.7498x over previous
//
#include <hip/hip_runtime.h>
#include <hip/hip_bf16.h>
#include <math.h>

#define B 64
#define T 128
#define S 128
#define E 512
#define H 1024
#define D 1024
#define KDIM 1024
#define G3 3072
#define JT 16

__device__ __forceinline__ float sigmoidf_(float x) { return 1.f / (1.f + expf(-x)); }

// ---------------------------------------------------------------------------
// 128x128-tile f32 GEMM: C[M,N] = A @ W^T (+bias). 8x8/thread, K-tile 16.
// SRC 0: plain A (lda). SRC 1: rows (b,tl) -> reversed_input (K=512).
// SRC 2: rows (b,tl) -> [y_states | rnn_flip] k-split at 1024 (K=2048).
// Row mapping (SRC 1/2): rg -> b = rg>>chLog, tl = rg & (CH-1); C row-major.
// (Proven correct in round-5 passing run.)
// ---------------------------------------------------------------------------
template<int SRC>
__global__ __launch_bounds__(256) void gemm128(
    const float* __restrict__ A1, const float* __restrict__ A2, int lda,
    const float* __restrict__ W, int ldw, const float* __restrict__ bias,
    float* __restrict__ C, int ldc, int Kd, int c0, int chLog) {
  __shared__ __align__(16) float As[16][132];
  __shared__ __align__(16) float Ws[16][132];
  const int bm = blockIdx.y * 128;
  const int bn = blockIdx.x * 128;
  const int tid = threadIdx.x;
  const int tr = tid >> 4, tc = tid & 15;
  float acc[8][8];
#pragma unroll
  for (int i = 0; i < 8; ++i)
#pragma unroll
    for (int j = 0; j < 8; ++j) acc[i][j] = 0.f;

  for (int k0 = 0; k0 < Kd; k0 += 16) {
#pragma unroll
    for (int l = 0; l < 8; ++l) {
      int i = tid + l * 256;
      int r = i >> 4, kk = i & 15;
      int rg = bm + r;
      int k = k0 + kk;
      float v;
      if (SRC == 0) {
        v = A1[(size_t)rg * lda + k];
      } else {
        int b = rg >> chLog, tl = rg & ((1 << chLog) - 1);
        int trow = b * T + c0 + tl;
        if (SRC == 1) v = A1[(size_t)trow * E + k];
        else v = (k < 1024) ? A1[(size_t)trow * 1024 + k]
                            : A2[(size_t)trow * 1024 + (k - 1024)];
      }
      As[kk][r] = v;
    }
#pragma unroll
    for (int l = 0; l < 8; ++l) {
      int i = tid + l * 256;
      int c = i >> 4, kk = i & 15;
      Ws[kk][c] = W[(size_t)(bn + c) * ldw + k0 + kk];
    }
    __syncthreads();
#pragma unroll
    for (int kk = 0; kk < 16; ++kk) {
      float a[8], w[8];
      *(float4*)&a[0] = *(const float4*)&As[kk][tr * 8];
      *(float4*)&a[4] = *(const float4*)&As[kk][tr * 8 + 4];
      *(float4*)&w[0] = *(const float4*)&Ws[kk][tc * 8];
      *(float4*)&w[4] = *(const float4*)&Ws[kk][tc * 8 + 4];
#pragma unroll
      for (int i = 0; i < 8; ++i)
#pragma unroll
        for (int j = 0; j < 8; ++j)
          acc[i][j] = fmaf(a[i], w[j], acc[i][j]);
    }
    __syncthreads();
  }
#pragma unroll
  for (int i = 0; i < 8; ++i) {
    int rg = bm + tr * 8 + i;
#pragma unroll
    for (int j = 0; j < 8; ++j) {
      int cc = bn + tc * 8 + j;
      float bv = bias ? bias[cc] : 0.f;
      C[(size_t)rg * ldc + cc] = acc[i][j] + bv;
    }
  }
}

// ---------------------------------------------------------------------------
// Scalar-broadcast skinny GEMM (proven rounds 2-7). Partials to part planes.
// ---------------------------------------------------------------------------
struct SBSeg { const float* A; const float* W; int lda; int ldw; int N; int colOff; };
struct SBArgs { SBSeg s[8]; };

__global__ __launch_bounds__(256) void sb_gemm(SBArgs args, int jtPerSeg, int Nstr,
                                               float* __restrict__ part) {
  const int seg = blockIdx.x / jtPerSeg;
  const int jt = blockIdx.x % jtPerSeg;
  const SBSeg sg = args.s[seg];
  const int j0 = jt * JT;
  if (j0 >= sg.N) return;
  const int wv = __builtin_amdgcn_readfirstlane(threadIdx.x >> 6);
  const int lane = threadIdx.x & 63;
  float a[128];
  const float4* ap = (const float4*)(sg.A + (size_t)lane * sg.lda + wv * 128);
#pragma unroll
  for (int q = 0; q < 32; ++q) {
    float4 v = ap[q];
    a[q * 4 + 0] = v.x; a[q * 4 + 1] = v.y; a[q * 4 + 2] = v.z; a[q * 4 + 3] = v.w;
  }
  float acc[JT];
#pragma unroll
  for (int jj = 0; jj < JT; ++jj) acc[jj] = 0.f;
#pragma unroll
  for (int jj = 0; jj < JT; ++jj) {
    int j = j0 + jj;
    if (j < sg.N) {
      const float4* wp = (const float4*)(sg.W + (size_t)j * sg.ldw + wv * 128);
      float s0 = 0.f, s1 = 0.f, s2 = 0.f, s3 = 0.f;
#pragma unroll
      for (int q = 0; q < 32; ++q) {
        float4 w4 = wp[q];
        s0 = fmaf(a[q * 4 + 0], w4.x, s0);
        s1 = fmaf(a[q * 4 + 1], w4.y, s1);
        s2 = fmaf(a[q * 4 + 2], w4.z, s2);
        s3 = fmaf(a[q * 4 + 3], w4.w, s3);
      }
      acc[jj] = (s0 + s1) + (s2 + s3);
    }
  }
  __shared__ float red[4][JT][64];
#pragma unroll
  for (int jj = 0; jj < JT; ++jj) red[wv][jj][lane] = acc[jj];
  __syncthreads();
  for (int idx = threadIdx.x; idx < JT * 64; idx += 256) {
    int jj = idx >> 6, b = idx & 63;
    int j = j0 + jj;
    if (j < sg.N) {
      float v = red[0][jj][b] + red[1][jj][b] + red[2][jj][b] + red[3][jj][b];
      part[((size_t)seg * Nstr + sg.colOff + j) * 64 + b] = v;
    }
  }
}

// ---------------------------------------------------------------------------
// GRU cell: gi from row-major biased gibuf [b*CH+tl][G3] + optional partial
// planes; gh = bhh + partial planes. LDS transpose for row-major h write
// (+ optional flipped copy). Grid 256 x 256 thr. (R3-proven, gi read adapted.)
// ---------------------------------------------------------------------------
__global__ __launch_bounds__(256) void gru_reduce(
    const float* __restrict__ part, const float* __restrict__ gi,
    int CH, int tl, int giPlanes, int ghStart, int ghPlanes,
    const float* __restrict__ bhh, float* __restrict__ hrow,
    float* __restrict__ flip_out, int t) {
  const int j0 = blockIdx.x * 4;
  const int jj = threadIdx.x >> 6;
  const int b = threadIdx.x & 63;
  const int j = j0 + jj;
  const float* gb = gi + (size_t)(b * CH + tl) * G3;
  float gir = gb[j];
  float giz = gb[H + j];
  float gin = gb[2 * H + j];
  for (int p2 = 0; p2 < giPlanes; ++p2) {
    const float* pp = part + (size_t)p2 * G3 * 64;
    gir += pp[(size_t)j * 64 + b];
    giz += pp[(size_t)(H + j) * 64 + b];
    gin += pp[(size_t)(2 * H + j) * 64 + b];
  }
  float ghr = bhh[j], ghz = bhh[H + j], ghn = bhh[2 * H + j];
  for (int p2 = ghStart; p2 < ghStart + ghPlanes; ++p2) {
    const float* pp = part + (size_t)p2 * G3 * 64;
    ghr += pp[(size_t)j * 64 + b];
    ghz += pp[(size_t)(H + j) * 64 + b];
    ghn += pp[(size_t)(2 * H + j) * 64 + b];
  }
  float r = sigmoidf_(gir + ghr);
  float z = sigmoidf_(giz + ghz);
  float n = tanhf(gin + r * ghn);
  float hold = hrow[(size_t)b * H + j];
  float hnew = (1.f - z) * n + z * hold;
  __shared__ float st[4][64];
  st[jj][b] = hnew;
  __syncthreads();
  int jl = threadIdx.x & 3, b2 = threadIdx.x >> 2;
  float v = st[jl][b2];
  hrow[(size_t)b2 * H + j0 + jl] = v;
  if (flip_out)
    flip_out[(size_t)b2 * T * H + (size_t)(T - 1 - t) * H + j0 + jl] = v;
}

// ---------------------------------------------------------------------------
// h-projections, full K=1024 in-block (4 waves x 256-float windows, streamed
// 32-float A chunks). Grid 385: corr(128, JT8) | query(128) | attv_h(128) |
// reward(1). Emits FINAL values: corrR/pq row-major, attH plane, reward+out.
// ---------------------------------------------------------------------------
__global__ __launch_bounds__(256) void hproj_gemm(
    const float* __restrict__ h,
    const float* __restrict__ corrW, const float* __restrict__ corrB,
    const float* __restrict__ qW, const float* __restrict__ avW,
    const float* __restrict__ rewW, const float* __restrict__ rewB,
    float* __restrict__ corrR, float* __restrict__ pq,
    float* __restrict__ attH, float* __restrict__ rew,
    float* __restrict__ out_rewards, int t) {
  const int task = blockIdx.x;
  const int tid = threadIdx.x;
  const int wv = __builtin_amdgcn_readfirstlane(tid >> 6);
  const int lane = tid & 63;
  const float* Wb; int ldw = 1024, n0, nrows, typ;
  if (task < 128)      { Wb = corrW; n0 = task * 8;         nrows = 8; typ = 0; }
  else if (task < 256) { Wb = qW;    n0 = (task - 128) * 8; nrows = 8; typ = 1; }
  else if (task < 384) { Wb = avW;   n0 = (task - 256) * 8; nrows = 8; typ = 2; ldw = 2048; }
  else                 { Wb = rewW;  n0 = 0;                nrows = 2; typ = 3; }
  const int k0 = wv * 256;                      // 4 waves x 256 = K=1024 (full)
  const float* arow = h + (size_t)lane * H + k0;
  float acc[8] = {0.f, 0.f, 0.f, 0.f, 0.f, 0.f, 0.f, 0.f};
  for (int sc = 0; sc < 8; ++sc) {
    float av[32];
    const float4* ap = (const float4*)(arow + sc * 32);
#pragma unroll
    for (int q = 0; q < 8; ++q) {
      float4 v = ap[q];
      av[4*q] = v.x; av[4*q+1] = v.y; av[4*q+2] = v.z; av[4*q+3] = v.w;
    }
#pragma unroll
    for (int rr = 0; rr < 8; ++rr) {
      if (rr < nrows) {
        const float4* wp = (const float4*)(Wb + (size_t)(n0 + rr) * ldw + k0 + sc * 32);
        float s = acc[rr];
#pragma unroll
        for (int q = 0; q < 8; ++q) {
          float4 w = wp[q];
          s = fmaf(av[4*q],   w.x, s);
          s = fmaf(av[4*q+1], w.y, s);
          s = fmaf(av[4*q+2], w.z, s);
          s = fmaf(av[4*q+3], w.w, s);
        }
        acc[rr] = s;
      }
    }
  }
  __shared__ float red[4][8][64];
#pragma unroll
  for (int rr = 0; rr < 8; ++rr) red[wv][rr][lane] = acc[rr];
  __syncthreads();
  for (int idx = tid; idx < 512; idx += 256) {
    int jj = idx >> 6, b = idx & 63;
    if (jj < nrows) {
      int n = n0 + jj;
      float v = red[0][jj][b] + red[1][jj][b] + red[2][jj][b] + red[3][jj][b];
      if (typ == 0) corrR[(size_t)b * 1024 + n] = v + corrB[n];
      else if (typ == 1) pq[(size_t)b * 1024 + n] = v;
      else if (typ == 2) attH[(size_t)n * 64 + b] = v;
      else {
        float rv = v + rewB[n];
        rew[n * 64 + b] = rv;
        out_rewards[((size_t)b * T + t) * 2 + n] = rv;
      }
    }
  }
}

// energies[b][s] = sum_j tanh(pq[b][j] + proj_keys[b][s][j]) * eW[j]
// Grid 2048 x 256 (wave per (b,s)). (R3-proven verbatim.)
__global__ __launch_bounds__(256) void energy_kernel(
    const float* __restrict__ pq, const float* __restrict__ pk,
    const float* __restrict__ eW, float* __restrict__ energies) {
  int wid = blockIdx.x * 4 + (threadIdx.x >> 6);
  int lane = threadIdx.x & 63;
  int b = wid >> 7, s = wid & 127;
  const float* pkp = pk + ((size_t)b * S + s) * H;
  const float* qp = pq + (size_t)b * H;
  float acc = 0.f;
#pragma unroll
  for (int i = 0; i < 16; ++i) {
    int j = lane + i * 64;
    acc += tanhf(qp[j] + pkp[j]) * eW[j];
  }
#pragma unroll
  for (int off = 32; off > 0; off >>= 1) acc += __shfl_down(acc, off);
  if (lane == 0) energies[b * S + s] = acc;
}

// Softmax (redundant per kt) + context quarter + corr finalize quarter +
// reward gate + outputs. Grid (64, 4) x 256 thr.
__global__ __launch_bounds__(256) void smct_plus(
    const float* __restrict__ energies, const float* __restrict__ enc,
    const float* __restrict__ corrR, const float* __restrict__ rew,
    float* __restrict__ ctx, float* __restrict__ uv,
    float* __restrict__ out_attns, float* __restrict__ out_corrs, int t) {
  int b = blockIdx.x, kt = blockIdx.y;
  int tid = threadIdx.x;
  __shared__ float se[128], sa[128], ss[128];
  if (tid < 128) { se[tid] = energies[b * S + tid]; sa[tid] = se[tid]; }
  __syncthreads();
  for (int st2 = 64; st2 > 0; st2 >>= 1) {
    if (tid < st2) sa[tid] = fmaxf(sa[tid], sa[tid + st2]);
    __syncthreads();
  }
  float mx = sa[0];
  __syncthreads();
  if (tid < 128) { sa[tid] = expf(se[tid] - mx); ss[tid] = sa[tid]; }
  __syncthreads();
  for (int st2 = 64; st2 > 0; st2 >>= 1) {
    if (tid < st2) ss[tid] += ss[tid + st2];
    __syncthreads();
  }
  float inv = 1.f / ss[0];
  __syncthreads();
  if (tid < 128) sa[tid] *= inv;   // alphas
  __syncthreads();
  int k = kt * 256 + tid;
  const float* eb = enc + (size_t)b * S * KDIM + k;
  float acc = 0.f;
#pragma unroll 4
  for (int s2 = 0; s2 < S; ++s2) acc = fmaf(sa[s2], eb[(size_t)s2 * KDIM], acc);
  ctx[(size_t)b * KDIM + k] = acc;
  // corr finalize (same k range)
  float r0 = rew[b], r1 = rew[64 + b];
  float g = (r1 > r0) ? 0.f : 1.f;
  float cv = g * tanhf(corrR[(size_t)b * 1024 + k]);
  uv[(size_t)b * 2048 + k] = cv;
  out_corrs[((size_t)b * T + t) * D + k] = cv;
  if (kt == 0 && tid < 128) out_attns[((size_t)b * T + t) * S + tid] = sa[tid];
}

// attv ctx-half GEMM + attH + bias + tanh -> uv att-half. Grid 128 x 256.
// (R7-proven structure; plane reads swapped for attH buffer.)
__global__ __launch_bounds__(256) void final_attv(
    const float* __restrict__ attH, const float* __restrict__ avW,
    const float* __restrict__ avB, const float* __restrict__ ctx,
    float* __restrict__ uv) {
  const int n0 = blockIdx.x * 8;
  const int tid = threadIdx.x;
  const int wv = __builtin_amdgcn_readfirstlane(tid >> 6);
  const int lane = tid & 63;
  __shared__ float red[4][8][64];
  float acc[8];
#pragma unroll
  for (int jj = 0; jj < 8; ++jj) acc[jj] = 0.f;
  const int k0 = wv * 256;                       // 4 waves x 256 = K=1024 (full)
  const float* arow = ctx + (size_t)lane * KDIM + k0;
  for (int sc = 0; sc < 8; ++sc) {
    float av[32];
    const float4* ap = (const float4*)(arow + sc * 32);
#pragma unroll
    for (int q = 0; q < 8; ++q) {
      float4 v = ap[q];
      av[4*q] = v.x; av[4*q+1] = v.y; av[4*q+2] = v.z; av[4*q+3] = v.w;
    }
#pragma unroll
    for (int jj = 0; jj < 8; ++jj) {
      const float4* wp = (const float4*)(avW + (size_t)(n0 + jj) * 2048 + 1024 + k0 + sc * 32);
      float s = acc[jj];
#pragma unroll
      for (int q = 0; q < 8; ++q) {
        float4 w = wp[q];
        s = fmaf(av[4*q],   w.x, s);
        s = fmaf(av[4*q+1], w.y, s);
        s = fmaf(av[4*q+2], w.z, s);
        s = fmaf(av[4*q+3], w.w, s);
      }
      acc[jj] = s;
    }
  }
#pragma unroll
  for (int jj = 0; jj < 8; ++jj) red[wv][jj][lane] = acc[jj];
  __syncthreads();
  for (int idx = tid; idx < 512; idx += 256) {
    int jj = idx >> 6, bb = idx & 63;
    int n = n0 + jj;
    float v = red[0][jj][bb] + red[1][jj][bb] + red[2][jj][bb] + red[3][jj][bb]
            + attH[(size_t)n * 64 + bb] + avB[n];
    uv[(size_t)bb * 2048 + 1024 + n] = tanhf(v);
  }
}

extern "C" void kernel_launch(void* const* d_in, const int* in_sizes, int n_in,
                              void* d_out, int out_size, void* d_ws, size_t ws_size,
                              hipStream_t stream) {
  const float* reversed_input = (const float*)d_in[0];
  const float* y_states = (const float*)d_in[3];
  const float* encoder = (const float*)d_in[4];
  const float* rnn_Wih = (const float*)d_in[6];
  const float* rnn_Whh = (const float*)d_in[7];
  const float* rnn_bih = (const float*)d_in[8];
  const float* rnn_bhh = (const float*)d_in[9];
  const float* out_Wih = (const float*)d_in[10];
  const float* out_Whh = (const float*)d_in[11];
  const float* out_bih = (const float*)d_in[12];
  const float* out_bhh = (const float*)d_in[13];
  const float* corr_W = (const float*)d_in[14];
  const float* corr_b = (const float*)d_in[15];
  const float* reward_W = (const float*)d_in[16];
  const float* reward_b = (const float*)d_in[17];
  const float* attv_W = (const float*)d_in[18];
  const float* attv_b = (const float*)d_in[19];
  const float* key_W = (const float*)d_in[20];
  const float* query_W = (const float*)d_in[21];
  const float* energy_W = (const float*)d_in[22];

  float* out_corrs = (float*)d_out;                    // (B,T,D)
  float* out_rewards = out_corrs + (size_t)B * T * D;  // (B,T,2)
  float* out_attns = out_rewards + (size_t)B * T * 2;  // (B,T,S)

  // workspace (floats)
  float* p = (float*)d_ws;
  float* rnn_flip = p;  p += (size_t)B * T * H;        // [b][t][j]
  float* proj_keys = p; p += (size_t)B * S * H;
  float* part = p;      p += (size_t)6 * G3 * 64;      // sb_gemm partial planes
  float* h = p;         p += (size_t)B * H;
  float* uv = p;        p += (size_t)B * 2048;         // [corr | att] row-major
  float* ctx = p;       p += (size_t)B * KDIM;
  float* corrR = p;     p += (size_t)B * 1024;
  float* pq = p;        p += (size_t)B * H;
  float* attH = p;      p += (size_t)H * 64;
  float* rew = p;       p += 128;
  float* energ = p;     p += (size_t)B * S;
  size_t fixedF = (size_t)(p - (float*)d_ws);
  const size_t perChunkRow = (size_t)G3;               // floats per (b,tl) row
  int CH = 8, chLog = 3;
  {
    int c = 64, l = 6;
    for (; c >= 8; c >>= 1, --l)
      if (ws_size >= (fixedF + (size_t)c * 64 * perChunkRow) * 4) break;
    if (c < 8) { c = 8; l = 3; }
    CH = c; chLog = l;
  }
  float* gibuf = p;  // CH*64 rows x G3, row-major [b*CH+tl][G3]

  hipMemsetAsync(h, 0, (size_t)B * H * sizeof(float), stream);
  hipMemsetAsync(uv, 0, (size_t)B * 2048 * sizeof(float), stream);

  dim3 blk(256);

  // proj_keys = encoder @ key_W^T  (128-tile)
  gemm128<0><<<dim3(H / 128, (B * S) / 128), blk, 0, stream>>>(
      encoder, nullptr, KDIM, key_W, KDIM, nullptr, proj_keys, H, KDIM, 0, 0);

  // ---- scan 1: backward GRU (2 launches/step) ----
  for (int c0 = 0; c0 < T; c0 += CH) {
    gemm128<1><<<dim3(G3 / 128, (64 * CH) / 128), blk, 0, stream>>>(
        reversed_input, nullptr, 0, rnn_Wih, E, rnn_bih, gibuf, G3, E, c0, chLog);
    for (int tl = 0; tl < CH; ++tl) {
      int t = c0 + tl;
      SBArgs s1{};
      s1.s[0] = { h, rnn_Whh, H, H, G3, 0 };
      s1.s[1] = { h + 512, rnn_Whh + 512, H, H, G3, 0 };
      sb_gemm<<<2 * 192, blk, 0, stream>>>(s1, 192, G3, part);
      gru_reduce<<<256, blk, 0, stream>>>(part, gibuf, CH, tl, 0, 0, 2,
                                          rnn_bhh, h, rnn_flip, t);
    }
  }

  // ---- scan 2: output GRU + attention (6 launches/step) ----
  hipMemsetAsync(h, 0, (size_t)B * H * sizeof(float), stream);
  for (int c0 = 0; c0 < T; c0 += CH) {
    gemm128<2><<<dim3(G3 / 128, (64 * CH) / 128), blk, 0, stream>>>(
        y_states, rnn_flip, 0, out_Wih, 4096, out_bih, gibuf, G3, 2048, c0, chLog);
    for (int tl = 0; tl < CH; ++tl) {
      int t = c0 + tl;
      // 1) gates GEMM: gi(uv, K=2048, 4 segs) + gh(h, K=1024, 2 segs)
      SBArgs k1{};
      for (int s2 = 0; s2 < 4; ++s2)
        k1.s[s2] = { uv + s2 * 512, out_Wih + 2048 + s2 * 512, 2048, 4096, G3, 0 };
      for (int s2 = 0; s2 < 2; ++s2)
        k1.s[4 + s2] = { h + s2 * 512, out_Whh + s2 * 512, H, H, G3, 0 };
      sb_gemm<<<6 * 192, blk, 0, stream>>>(k1, 192, G3, part);
      // 2) GRU cell
      gru_reduce<<<256, blk, 0, stream>>>(part, gibuf, CH, tl, 4, 4, 2,
                                          out_bhh, h, nullptr, t);
      // 3) h-projections (full K in-block, final values)
      hproj_gemm<<<385, blk, 0, stream>>>(h, corr_W, corr_b, query_W, attv_W,
                                          reward_W, reward_b, corrR, pq, attH,
                                          rew, out_rewards, t);
      // 4) energies
      energy_kernel<<<2048, blk, 0, stream>>>(pq, proj_keys, energy_W, energ);
      // 5) softmax + context + corr finalize + outputs
      smct_plus<<<dim3(B, 4), blk, 0, stream>>>(energ, encoder, corrR, rew,
                                                ctx, uv, out_attns, out_corrs, t);
      // 6) attv ctx-half + combine -> uv att-half
      final_attv<<<128, blk, 0, stream>>>(attH, attv_W, attv_b, ctx, uv);
    }
  }
}